// Round 2
// 1751.373 us; speedup vs baseline: 1.0380x; 1.0380x over previous
//
#include <hip/hip_runtime.h>

typedef __bf16 bf16;
typedef float f32x4 __attribute__((ext_vector_type(4)));
typedef bf16 bf16x8 __attribute__((ext_vector_type(8)));
typedef bf16 bf16x4 __attribute__((ext_vector_type(4)));

constexpr int Bc = 4, Sc = 2048, Dc = 1024, Hc = 16, DKc = 64;
constexpr float NEGc = -10000.0f;

// ---------------------------------------------------------------------------
// Kernel 1: QKV projection GEMM.  y = x @ W^T + b, x:[8192,1024] W:[1024,1024]
// both K-contiguous (B^T pattern).  Output bf16 head-major [B,H,S,64].
// 128x128 tile, BK=32, 4 waves in 2x2, 16 MFMA 16x16x32 per wave per K-iter.
// ---------------------------------------------------------------------------
__global__ __launch_bounds__(256, 2) void proj_kernel(
    const float* __restrict__ xq, const float* __restrict__ xk, const float* __restrict__ xv,
    const float* __restrict__ Wq, const float* __restrict__ bq,
    const float* __restrict__ Wk, const float* __restrict__ bk,
    const float* __restrict__ Wv, const float* __restrict__ bv,
    bf16* __restrict__ qh, bf16* __restrict__ kh, bf16* __restrict__ vh)
{
    const int z = blockIdx.z;
    const float* x    = (z == 0) ? xq : (z == 1) ? xk : xv;
    const float* W    = (z == 0) ? Wq : (z == 1) ? Wk : Wv;
    const float* bias = (z == 0) ? bq : (z == 1) ? bk : bv;
    bf16* dst         = (z == 0) ? qh : (z == 1) ? kh : vh;

    const int tid = threadIdx.x;
    const int wave = tid >> 6, lane = tid & 63, quad = lane >> 4, m16 = lane & 15;
    const int wm = (wave >> 1) * 64, wn = (wave & 1) * 64;
    const int m0 = blockIdx.y * 128, n0 = blockIdx.x * 128;

    // stride 40 bf16 = 20 words: quad lanes land 2-way per bank (free, m136)
    __shared__ bf16 As[128][40];
    __shared__ bf16 Bs[128][40];

    const f32x4 zero4 = {0.f, 0.f, 0.f, 0.f};
    f32x4 acc[4][4];
#pragma unroll
    for (int i = 0; i < 4; i++)
#pragma unroll
        for (int j = 0; j < 4; j++) acc[i][j] = zero4;

    for (int kk = 0; kk < 32; ++kk) {
        const int k0 = kk * 32;
#pragma unroll
        for (int i = 0; i < 4; i++) {
            int f4 = tid + i * 256;            // 0..1023 float4 slots (128 rows x 8)
            int r = f4 >> 3, c4 = (f4 & 7) * 4;
            float4 a = *(const float4*)&x[(size_t)(m0 + r) * Dc + k0 + c4];
            float4 w = *(const float4*)&W[(size_t)(n0 + r) * Dc + k0 + c4];
            bf16x4 av; av.x = (bf16)a.x; av.y = (bf16)a.y; av.z = (bf16)a.z; av.w = (bf16)a.w;
            bf16x4 wv; wv.x = (bf16)w.x; wv.y = (bf16)w.y; wv.z = (bf16)w.z; wv.w = (bf16)w.w;
            *(bf16x4*)&As[r][c4] = av;
            *(bf16x4*)&Bs[r][c4] = wv;
        }
        __syncthreads();
        bf16x8 af[4], bfr[4];
#pragma unroll
        for (int t = 0; t < 4; t++) {
            af[t]  = *(const bf16x8*)&As[wm + t * 16 + m16][quad * 8];
            bfr[t] = *(const bf16x8*)&Bs[wn + t * 16 + m16][quad * 8];
        }
#pragma unroll
        for (int mt = 0; mt < 4; mt++)
#pragma unroll
            for (int nt = 0; nt < 4; nt++)
                acc[mt][nt] = __builtin_amdgcn_mfma_f32_16x16x32_bf16(af[mt], bfr[nt], acc[mt][nt], 0, 0, 0);
        __syncthreads();
    }

    // epilogue: +bias, scatter bf16 to [B,H,S,64]
#pragma unroll
    for (int nt = 0; nt < 4; nt++) {
        int n = n0 + wn + nt * 16 + m16;
        float bval = bias[n];
        int h = n >> 6, d = n & 63;
#pragma unroll
        for (int mt = 0; mt < 4; mt++) {
#pragma unroll
            for (int r = 0; r < 4; r++) {
                int m = m0 + wm + mt * 16 + quad * 4 + r;
                int bb = m >> 11, s = m & 2047;     // S = 2048
                float val = acc[mt][nt][r] + bval;
                dst[(((size_t)(bb * Hc + h)) * Sc + s) * DKc + d] = (bf16)val;
            }
        }
    }
}

// ---------------------------------------------------------------------------
// Kernel 2: transpose V  [B,H,S,64] -> [B,H,64,S]  (so PV B-frags are 16B loads)
// ---------------------------------------------------------------------------
__global__ __launch_bounds__(256) void vtrans_kernel(const bf16* __restrict__ vh,
                                                     bf16* __restrict__ vt)
{
    const int tid = threadIdx.x;
    const int bh = blockIdx.y, s0 = blockIdx.x * 64;
    __shared__ bf16 tile[64][72];   // 144 B rows (16B multiple), banks spread
    const bf16* src = vh + ((size_t)bh * Sc + s0) * DKc;
#pragma unroll
    for (int i = 0; i < 2; i++) {
        int v = tid + i * 256;           // 0..511 vec8 units
        int sl = v >> 3, d8 = (v & 7) * 8;
        *(bf16x8*)&tile[sl][d8] = *(const bf16x8*)&src[sl * DKc + d8];
    }
    __syncthreads();
#pragma unroll
    for (int i = 0; i < 2; i++) {
        int v = tid + i * 256;
        int d = v >> 3, s8 = (v & 7) * 8;
        bf16x8 o;
#pragma unroll
        for (int j = 0; j < 8; j++) o[j] = tile[s8 + j][d];
        *(bf16x8*)&vt[((size_t)bh * DKc + d) * Sc + s0 + s8] = o;
    }
}

// ---------------------------------------------------------------------------
// Kernel 3: attention.  One block = (b, h, 16 q-rows).  Scores for the LIVE
// (causal-visible) key range kept in registers (C-frag layout); the causal-dead
// upper region is provably exact-zero in fp32 whenever the visible row max is
// > -5000, so its QK^T / mask / exp / PV work is skipped and the probs are
// zero-filled with vectorized NT stores.  Rare all-visible-masked rows are
// detected from the reduced row max and fall back to the exact full path.
// PV staging uses a 16x256 bf16 LDS chunk (8 KB, XOR-8 swizzled) instead of a
// 64 KB full-row buffer; __launch_bounds__(256,3) -> 3 blocks/CU.
// ---------------------------------------------------------------------------
__global__ __launch_bounds__(256, 3) void attn_kernel(
    const bf16* __restrict__ qh, const bf16* __restrict__ kh, const bf16* __restrict__ vt,
    const int* __restrict__ mask, float* __restrict__ attn_out, float* __restrict__ out)
{
    // heavy (large qtr) blocks first: dispatch is ascending blockIdx.x
    const int qtr = (int)gridDim.x - 1 - (int)blockIdx.x;
    const int h = blockIdx.y, b = blockIdx.z;
    const int bh = b * Hc + h, q0 = qtr * 16;
    const int tid = threadIdx.x;
    const int wave = tid >> 6, lane = tid & 63, quad = lane >> 4, m16 = lane & 15;

    __shared__ bf16 sc[16][256];        // prob chunk (bf16, XOR-8 swizzled): 8 KB
    __shared__ float red[128];          // cross-wave reduction scratch

    const bf16* qrow = qh + ((size_t)bh * Sc + q0) * DKc;
    const bf16* krow = kh + (size_t)bh * Sc * DKc;
    const bf16* vrow = vt + (size_t)bh * DKc * Sc;
    const int*  mrow = mask + (size_t)b * Sc * Sc;

    // Q fragments (rows q0..q0+15), K-dim split 0..31 / 32..63
    const bf16x8 aq0 = *(const bf16x8*)&qrow[m16 * DKc + quad * 8];
    const bf16x8 aq1 = *(const bf16x8*)&qrow[m16 * DKc + 32 + quad * 8];

    const f32x4 zero4 = {0.f, 0.f, 0.f, 0.f};
    f32x4 acc[32];
#pragma unroll
    for (int t = 0; t < 32; t++) acc[t] = zero4;

    const int gq = qtr >> 4;            // last 256-key chunk touching the lower triangle

    // ---- stage 1 QK^T: chunks 0..gq (group-guarded; straight-line inside) ----
#pragma unroll
    for (int g = 0; g < 8; g++) {
        if (g <= gq) {
#pragma unroll
            for (int tp = 0; tp < 4; tp++) {
                const int t = g * 4 + tp;
                const int n0 = (t * 4 + wave) * 16;
                const bf16* kb = &krow[(size_t)(n0 + m16) * DKc + quad * 8];
                bf16x8 b0 = *(const bf16x8*)kb;
                bf16x8 b1 = *(const bf16x8*)(kb + 32);
                acc[t] = __builtin_amdgcn_mfma_f32_16x16x32_bf16(aq0, b0, acc[t], 0, 0, 0);
                acc[t] = __builtin_amdgcn_mfma_f32_16x16x32_bf16(aq1, b1, acc[t], 0, 0, 0);
            }
        }
    }

    // ---- scale + mask adders + running max, exactly over j <= qtr ----
    float rmax[4] = {-3e38f, -3e38f, -3e38f, -3e38f};
#pragma unroll
    for (int t = 0; t < 32; t++) {
        const int j = t * 4 + wave;
        if (j <= qtr) {
            const int kcol = j * 16 + m16;
#pragma unroll
            for (int r = 0; r < 4; r++) {
                const int grow = q0 + quad * 4 + r;
                const int mv = mrow[(size_t)grow * Sc + kcol];
                float s = acc[t][r] * 0.125f;
                s += (mv == 0) ? NEGc : 0.f;        // padding mask adder
                s += (kcol > grow) ? NEGc : 0.f;    // causal adder (diagonal tile)
                acc[t][r] = s;
                rmax[r] = fmaxf(rmax[r], s);
            }
        }
    }
#pragma unroll
    for (int off = 1; off < 16; off <<= 1)
#pragma unroll
        for (int r = 0; r < 4; r++) rmax[r] = fmaxf(rmax[r], __shfl_xor(rmax[r], off, 64));
    if (m16 == 0) {
#pragma unroll
        for (int r = 0; r < 4; r++) red[wave * 16 + quad * 4 + r] = rmax[r];
    }
    __syncthreads();
#pragma unroll
    for (int r = 0; r < 4; r++) {
        const int row = quad * 4 + r;
        rmax[r] = fmaxf(fmaxf(red[row], red[16 + row]), fmaxf(red[32 + row], red[48 + row]));
    }

    // rare-path detector: visible max <= -5000 <=> whole visible span is
    // padding-masked, so causal-masked (~-1e4) scores participate in softmax.
    float mn = fminf(fminf(rmax[0], rmax[1]), fminf(rmax[2], rmax[3]));
    mn = fminf(mn, __shfl_xor(mn, 16, 64));
    mn = fminf(mn, __shfl_xor(mn, 32, 64));
    const bool needfull = (mn <= -5000.0f);        // block-uniform
    int Jmax = qtr;

    if (needfull) {
        __syncthreads();                            // red[0..63] readers done
#pragma unroll
        for (int g = 0; g < 8; g++) {
            if (g > gq) {
#pragma unroll
                for (int tp = 0; tp < 4; tp++) {
                    const int t = g * 4 + tp;
                    const int n0 = (t * 4 + wave) * 16;
                    const bf16* kb = &krow[(size_t)(n0 + m16) * DKc + quad * 8];
                    bf16x8 b0 = *(const bf16x8*)kb;
                    bf16x8 b1 = *(const bf16x8*)(kb + 32);
                    acc[t] = __builtin_amdgcn_mfma_f32_16x16x32_bf16(aq0, b0, acc[t], 0, 0, 0);
                    acc[t] = __builtin_amdgcn_mfma_f32_16x16x32_bf16(aq1, b1, acc[t], 0, 0, 0);
                }
            }
        }
#pragma unroll
        for (int t = 0; t < 32; t++) {
            const int j = t * 4 + wave;
            if (j > qtr) {
                const int kcol = j * 16 + m16;
#pragma unroll
                for (int r = 0; r < 4; r++) {
                    const int grow = q0 + quad * 4 + r;
                    const int mv = mrow[(size_t)grow * Sc + kcol];
                    float s = acc[t][r] * 0.125f;
                    s += (mv == 0) ? NEGc : 0.f;
                    s += (kcol > grow) ? NEGc : 0.f;
                    acc[t][r] = s;
                    rmax[r] = fmaxf(rmax[r], s);
                }
            }
        }
#pragma unroll
        for (int off = 1; off < 16; off <<= 1)
#pragma unroll
            for (int r = 0; r < 4; r++) rmax[r] = fmaxf(rmax[r], __shfl_xor(rmax[r], off, 64));
        if (m16 == 0) {
#pragma unroll
            for (int r = 0; r < 4; r++) red[wave * 16 + quad * 4 + r] = rmax[r];
        }
        __syncthreads();
#pragma unroll
        for (int r = 0; r < 4; r++) {
            const int row = quad * 4 + r;
            rmax[r] = fmaxf(fmaxf(red[row], red[16 + row]), fmaxf(red[32 + row], red[48 + row]));
        }
        Jmax = 127;
    }

    // ---- exp + sum over live tiles ----
    float rsum[4] = {0.f, 0.f, 0.f, 0.f};
#pragma unroll
    for (int t = 0; t < 32; t++) {
        const int j = t * 4 + wave;
        if (j <= Jmax) {
#pragma unroll
            for (int r = 0; r < 4; r++) {
                float e = __expf(acc[t][r] - rmax[r]);
                acc[t][r] = e;
                rsum[r] += e;
            }
        }
    }
#pragma unroll
    for (int off = 1; off < 16; off <<= 1)
#pragma unroll
        for (int r = 0; r < 4; r++) rsum[r] += __shfl_xor(rsum[r], off, 64);
    if (m16 == 0) {
#pragma unroll
        for (int r = 0; r < 4; r++) red[64 + wave * 16 + quad * 4 + r] = rsum[r];
    }
    __syncthreads();
    float inv[4];
#pragma unroll
    for (int r = 0; r < 4; r++) {
        const int row = quad * 4 + r;
        inv[r] = 1.0f / (red[64 + row] + red[80 + row] + red[96 + row] + red[112 + row]);
    }

    // ---- normalized probs: NT fp32 to global; acc overwritten with p ----
    float* arow_base = attn_out + ((size_t)bh * Sc + q0) * Sc;
#pragma unroll
    for (int t = 0; t < 32; t++) {
        const int j = t * 4 + wave;
        if (j <= Jmax) {
            const int kcol = j * 16 + m16;
#pragma unroll
            for (int r = 0; r < 4; r++) {
                const int row = quad * 4 + r;
                const float p = acc[t][r] * inv[r];
                acc[t][r] = p;
                __builtin_nontemporal_store(p, &arow_base[(size_t)row * Sc + kcol]);
            }
        }
    }
    // zero-fill the causal-dead region (exact in fp32), vectorized NT f32x4
    if (!needfull) {
        const int z0 = (qtr + 1) * 16;
        const int c4n = (Sc - z0) >> 2;
#pragma unroll
        for (int r = 0; r < 16; r++) {
            float* rp = arow_base + (size_t)r * Sc + z0;
            for (int c = tid; c < c4n; c += 256)
                __builtin_nontemporal_store(zero4, (f32x4*)(rp + 4 * c));
        }
    }

    // ---- PV over live 256-key chunks: LDS-stage bf16 probs, MFMA vs V^T ----
    const int dcol = wave * 16 + m16;
    const bf16* vbase = &vrow[(size_t)dcol * Sc];
    const int swz = (m16 & 7) << 3;
    f32x4 oacc = zero4;
#pragma unroll
    for (int c = 0; c < 8; c++) {
        if (c * 16 <= Jmax) {
            __syncthreads();                    // prev chunk's reads done
#pragma unroll
            for (int tp = 0; tp < 4; tp++) {
                const int t = c * 4 + tp;
                const int j = t * 4 + wave;
                const int lc = (tp * 4 + wave) * 16 + m16;   // chunk-local col
                if (j <= Jmax) {
#pragma unroll
                    for (int r = 0; r < 4; r++) {
                        const int row = quad * 4 + r;
                        sc[row][lc ^ ((row & 7) << 3)] = (bf16)acc[t][r];
                    }
                } else if (j <= (Jmax | 1)) {   // odd partner of a live 32-key group
#pragma unroll
                    for (int r = 0; r < 4; r++) {
                        const int row = quad * 4 + r;
                        sc[row][lc ^ ((row & 7) << 3)] = (bf16)0.f;
                    }
                }
            }
            __syncthreads();
#pragma unroll
            for (int lks = 0; lks < 8; lks++) {
                if (c * 16 + 2 * lks <= Jmax) {
                    const int k0 = lks * 32 + quad * 8;
                    bf16x8 a  = *(const bf16x8*)&sc[m16][k0 ^ swz];
                    bf16x8 b8 = *(const bf16x8*)&vbase[c * 256 + k0];
                    oacc = __builtin_amdgcn_mfma_f32_16x16x32_bf16(a, b8, oacc, 0, 0, 0);
                }
            }
        }
    }
    float* obase = out + ((size_t)(b * Sc + q0)) * Dc + h * DKc;
#pragma unroll
    for (int r = 0; r < 4; r++) {
        const int row = quad * 4 + r;
        obase[(size_t)row * Dc + dcol] = oacc[r];
    }
}

// ---------------------------------------------------------------------------
// Kernel 4: residual add + LayerNorm, in place on d_out's `out` region.
// ---------------------------------------------------------------------------
__global__ __launch_bounds__(256) void ln_kernel(float* __restrict__ out,
                                                 const float* __restrict__ resid,
                                                 const float* __restrict__ gw,
                                                 const float* __restrict__ bw)
{
    const int row = blockIdx.x, tid = threadIdx.x;
    float* orow = out + (size_t)row * Dc;
    const float* rrow = resid + (size_t)row * Dc;
    float4 x = *(const float4*)&orow[tid * 4];
    float4 rr = *(const float4*)&rrow[tid * 4];
    x.x += rr.x; x.y += rr.y; x.z += rr.z; x.w += rr.w;
    float s1 = x.x + x.y + x.z + x.w;
    float s2 = x.x * x.x + x.y * x.y + x.z * x.z + x.w * x.w;
#pragma unroll
    for (int off = 1; off < 64; off <<= 1) {
        s1 += __shfl_xor(s1, off, 64);
        s2 += __shfl_xor(s2, off, 64);
    }
    __shared__ float red[8];
    const int wave = tid >> 6, lane = tid & 63;
    if (lane == 0) { red[wave] = s1; red[4 + wave] = s2; }
    __syncthreads();
    s1 = red[0] + red[1] + red[2] + red[3];
    s2 = red[4] + red[5] + red[6] + red[7];
    const float mu = s1 * (1.f / Dc);
    const float var = s2 * (1.f / Dc) - mu * mu;
    const float rstd = rsqrtf(var + 1e-5f);
    float4 g4 = *(const float4*)&gw[tid * 4];
    float4 b4 = *(const float4*)&bw[tid * 4];
    float4 y;
    y.x = (x.x - mu) * rstd * g4.x + b4.x;
    y.y = (x.y - mu) * rstd * g4.y + b4.y;
    y.z = (x.z - mu) * rstd * g4.z + b4.z;
    y.w = (x.w - mu) * rstd * g4.w + b4.w;
    *(float4*)&orow[tid * 4] = y;
}

// ---------------------------------------------------------------------------
extern "C" void kernel_launch(void* const* d_in, const int* in_sizes, int n_in,
                              void* d_out, int out_size, void* d_ws, size_t ws_size,
                              hipStream_t stream)
{
    (void)in_sizes; (void)n_in; (void)out_size; (void)ws_size;
    const float* q    = (const float*)d_in[0];
    const float* k    = (const float*)d_in[1];
    const float* v    = (const float*)d_in[2];
    const int*   mask = (const int*)d_in[3];
    const float* Wq   = (const float*)d_in[4];
    const float* bq   = (const float*)d_in[5];
    const float* Wk   = (const float*)d_in[6];
    const float* bk   = (const float*)d_in[7];
    const float* Wv   = (const float*)d_in[8];
    const float* bv   = (const float*)d_in[9];
    const float* g    = (const float*)d_in[10];
    const float* bet  = (const float*)d_in[11];

    float* out  = (float*)d_out;                     // [B,S,D]
    float* attn = out + (size_t)Bc * Sc * Dc;        // [B,H,S,S]

    const size_t headN = (size_t)Bc * Hc * Sc * DKc; // 8.39M bf16 = 16 MB
    bf16* qh = (bf16*)d_ws;
    bf16* kh = qh + headN;
    bf16* vh = kh + headN;
    bf16* vt = vh + headN;

    proj_kernel<<<dim3(8, 64, 3), 256, 0, stream>>>(q, k, v, Wq, bq, Wk, bk, Wv, bv, qh, kh, vh);
    vtrans_kernel<<<dim3(Sc / 64, Bc * Hc), 256, 0, stream>>>(vh, vt);
    attn_kernel<<<dim3(Sc / 16, Hc, Bc), 256, 0, stream>>>(qh, kh, vt, mask, attn, out);
    ln_kernel<<<dim3(Bc * Sc), 256, 0, stream>>>(out, q, g, bet);
}

// Round 3
// 1667.048 us; speedup vs baseline: 1.0905x; 1.0506x over previous
//
#include <hip/hip_runtime.h>

typedef __bf16 bf16;
typedef float f32x4 __attribute__((ext_vector_type(4)));
typedef bf16 bf16x8 __attribute__((ext_vector_type(8)));
typedef bf16 bf16x4 __attribute__((ext_vector_type(4)));

constexpr int Bc = 4, Sc = 2048, Dc = 1024, Hc = 16, DKc = 64;
constexpr float NEGc = -10000.0f;

// ---------------------------------------------------------------------------
// Kernel 1: QKV projection GEMM.  y = x @ W^T + b, x:[8192,1024] W:[1024,1024]
// both K-contiguous (B^T pattern).  Output bf16 head-major [B,H,S,64].
// 128x128 tile, BK=32, 4 waves in 2x2, 16 MFMA 16x16x32 per wave per K-iter.
// ---------------------------------------------------------------------------
__global__ __launch_bounds__(256, 2) void proj_kernel(
    const float* __restrict__ xq, const float* __restrict__ xk, const float* __restrict__ xv,
    const float* __restrict__ Wq, const float* __restrict__ bq,
    const float* __restrict__ Wk, const float* __restrict__ bk,
    const float* __restrict__ Wv, const float* __restrict__ bv,
    bf16* __restrict__ qh, bf16* __restrict__ kh, bf16* __restrict__ vh)
{
    const int z = blockIdx.z;
    const float* x    = (z == 0) ? xq : (z == 1) ? xk : xv;
    const float* W    = (z == 0) ? Wq : (z == 1) ? Wk : Wv;
    const float* bias = (z == 0) ? bq : (z == 1) ? bk : bv;
    bf16* dst         = (z == 0) ? qh : (z == 1) ? kh : vh;

    const int tid = threadIdx.x;
    const int wave = tid >> 6, lane = tid & 63, quad = lane >> 4, m16 = lane & 15;
    const int wm = (wave >> 1) * 64, wn = (wave & 1) * 64;
    const int m0 = blockIdx.y * 128, n0 = blockIdx.x * 128;

    // stride 40 bf16 = 20 words: quad lanes land 2-way per bank (free, m136)
    __shared__ bf16 As[128][40];
    __shared__ bf16 Bs[128][40];

    const f32x4 zero4 = {0.f, 0.f, 0.f, 0.f};
    f32x4 acc[4][4];
#pragma unroll
    for (int i = 0; i < 4; i++)
#pragma unroll
        for (int j = 0; j < 4; j++) acc[i][j] = zero4;

    for (int kk = 0; kk < 32; ++kk) {
        const int k0 = kk * 32;
#pragma unroll
        for (int i = 0; i < 4; i++) {
            int f4 = tid + i * 256;            // 0..1023 float4 slots (128 rows x 8)
            int r = f4 >> 3, c4 = (f4 & 7) * 4;
            float4 a = *(const float4*)&x[(size_t)(m0 + r) * Dc + k0 + c4];
            float4 w = *(const float4*)&W[(size_t)(n0 + r) * Dc + k0 + c4];
            bf16x4 av; av.x = (bf16)a.x; av.y = (bf16)a.y; av.z = (bf16)a.z; av.w = (bf16)a.w;
            bf16x4 wv; wv.x = (bf16)w.x; wv.y = (bf16)w.y; wv.z = (bf16)w.z; wv.w = (bf16)w.w;
            *(bf16x4*)&As[r][c4] = av;
            *(bf16x4*)&Bs[r][c4] = wv;
        }
        __syncthreads();
        bf16x8 af[4], bfr[4];
#pragma unroll
        for (int t = 0; t < 4; t++) {
            af[t]  = *(const bf16x8*)&As[wm + t * 16 + m16][quad * 8];
            bfr[t] = *(const bf16x8*)&Bs[wn + t * 16 + m16][quad * 8];
        }
#pragma unroll
        for (int mt = 0; mt < 4; mt++)
#pragma unroll
            for (int nt = 0; nt < 4; nt++)
                acc[mt][nt] = __builtin_amdgcn_mfma_f32_16x16x32_bf16(af[mt], bfr[nt], acc[mt][nt], 0, 0, 0);
        __syncthreads();
    }

    // epilogue: +bias, scatter bf16 to [B,H,S,64]
#pragma unroll
    for (int nt = 0; nt < 4; nt++) {
        int n = n0 + wn + nt * 16 + m16;
        float bval = bias[n];
        int h = n >> 6, d = n & 63;
#pragma unroll
        for (int mt = 0; mt < 4; mt++) {
#pragma unroll
            for (int r = 0; r < 4; r++) {
                int m = m0 + wm + mt * 16 + quad * 4 + r;
                int bb = m >> 11, s = m & 2047;     // S = 2048
                float val = acc[mt][nt][r] + bval;
                dst[(((size_t)(bb * Hc + h)) * Sc + s) * DKc + d] = (bf16)val;
            }
        }
    }
}

// ---------------------------------------------------------------------------
// Kernel 2: transpose V  [B,H,S,64] -> [B,H,64,S]  (so PV B-frags are 16B loads)
// ---------------------------------------------------------------------------
__global__ __launch_bounds__(256) void vtrans_kernel(const bf16* __restrict__ vh,
                                                     bf16* __restrict__ vt)
{
    const int tid = threadIdx.x;
    const int bh = blockIdx.y, s0 = blockIdx.x * 64;
    __shared__ bf16 tile[64][72];   // 144 B rows (16B multiple), banks spread
    const bf16* src = vh + ((size_t)bh * Sc + s0) * DKc;
#pragma unroll
    for (int i = 0; i < 2; i++) {
        int v = tid + i * 256;           // 0..511 vec8 units
        int sl = v >> 3, d8 = (v & 7) * 8;
        *(bf16x8*)&tile[sl][d8] = *(const bf16x8*)&src[sl * DKc + d8];
    }
    __syncthreads();
#pragma unroll
    for (int i = 0; i < 2; i++) {
        int v = tid + i * 256;
        int d = v >> 3, s8 = (v & 7) * 8;
        bf16x8 o;
#pragma unroll
        for (int j = 0; j < 8; j++) o[j] = tile[s8 + j][d];
        *(bf16x8*)&vt[((size_t)bh * DKc + d) * Sc + s0 + s8] = o;
    }
}

// ---------------------------------------------------------------------------
// Kernel 3: attention.  One block = (b, h, 16 q-rows).  Scores for the LIVE
// (causal-visible) key range kept in registers (C-frag layout); the causal-dead
// upper region is provably exact-zero in fp32 whenever the visible row max is
// > -5000, so its QK^T / mask / exp / PV work is skipped and the probs are
// zero-filled with vectorized NT stores.  Rare all-visible-masked rows are
// detected from the reduced row max and fall back to the exact full path.
// PV staging uses a 16x256 bf16 LDS chunk (8 KB, XOR-8 swizzled).
// __launch_bounds__(256,2): acc[32] f32x4 = 128 VGPR must stay in registers —
// (256,3) forced ~168-reg cap and spilled accumulators to scratch (R2: only
// -9% despite -47% work).  2 blocks/CU, zero spill.
// ---------------------------------------------------------------------------
__global__ __launch_bounds__(256, 2) void attn_kernel(
    const bf16* __restrict__ qh, const bf16* __restrict__ kh, const bf16* __restrict__ vt,
    const int* __restrict__ mask, float* __restrict__ attn_out, float* __restrict__ out)
{
    // heavy (large qtr) blocks first: dispatch is ascending blockIdx.x
    const int qtr = (int)gridDim.x - 1 - (int)blockIdx.x;
    const int h = blockIdx.y, b = blockIdx.z;
    const int bh = b * Hc + h, q0 = qtr * 16;
    const int tid = threadIdx.x;
    const int wave = tid >> 6, lane = tid & 63, quad = lane >> 4, m16 = lane & 15;

    __shared__ bf16 sc[16][256];        // prob chunk (bf16, XOR-8 swizzled): 8 KB
    __shared__ float red[128];          // cross-wave reduction scratch

    const bf16* qrow = qh + ((size_t)bh * Sc + q0) * DKc;
    const bf16* krow = kh + (size_t)bh * Sc * DKc;
    const bf16* vrow = vt + (size_t)bh * DKc * Sc;
    const int*  mrow = mask + (size_t)b * Sc * Sc;

    // Q fragments (rows q0..q0+15), K-dim split 0..31 / 32..63
    const bf16x8 aq0 = *(const bf16x8*)&qrow[m16 * DKc + quad * 8];
    const bf16x8 aq1 = *(const bf16x8*)&qrow[m16 * DKc + 32 + quad * 8];

    const f32x4 zero4 = {0.f, 0.f, 0.f, 0.f};
    f32x4 acc[32];
#pragma unroll
    for (int t = 0; t < 32; t++) acc[t] = zero4;

    const int gq = qtr >> 4;            // last 256-key chunk touching the lower triangle

    // ---- stage 1 QK^T: chunks 0..gq (group-guarded; straight-line inside) ----
#pragma unroll
    for (int g = 0; g < 8; g++) {
        if (g <= gq) {
#pragma unroll
            for (int tp = 0; tp < 4; tp++) {
                const int t = g * 4 + tp;
                const int n0 = (t * 4 + wave) * 16;
                const bf16* kb = &krow[(size_t)(n0 + m16) * DKc + quad * 8];
                bf16x8 b0 = *(const bf16x8*)kb;
                bf16x8 b1 = *(const bf16x8*)(kb + 32);
                acc[t] = __builtin_amdgcn_mfma_f32_16x16x32_bf16(aq0, b0, acc[t], 0, 0, 0);
                acc[t] = __builtin_amdgcn_mfma_f32_16x16x32_bf16(aq1, b1, acc[t], 0, 0, 0);
            }
        }
    }

    // ---- scale + mask adders + running max, exactly over j <= qtr ----
    float rmax[4] = {-3e38f, -3e38f, -3e38f, -3e38f};
#pragma unroll
    for (int t = 0; t < 32; t++) {
        const int j = t * 4 + wave;
        if (j <= qtr) {
            const int kcol = j * 16 + m16;
#pragma unroll
            for (int r = 0; r < 4; r++) {
                const int grow = q0 + quad * 4 + r;
                const int mv = mrow[(size_t)grow * Sc + kcol];
                float s = acc[t][r] * 0.125f;
                s += (mv == 0) ? NEGc : 0.f;        // padding mask adder
                s += (kcol > grow) ? NEGc : 0.f;    // causal adder (diagonal tile)
                acc[t][r] = s;
                rmax[r] = fmaxf(rmax[r], s);
            }
        }
    }
#pragma unroll
    for (int off = 1; off < 16; off <<= 1)
#pragma unroll
        for (int r = 0; r < 4; r++) rmax[r] = fmaxf(rmax[r], __shfl_xor(rmax[r], off, 64));
    if (m16 == 0) {
#pragma unroll
        for (int r = 0; r < 4; r++) red[wave * 16 + quad * 4 + r] = rmax[r];
    }
    __syncthreads();
#pragma unroll
    for (int r = 0; r < 4; r++) {
        const int row = quad * 4 + r;
        rmax[r] = fmaxf(fmaxf(red[row], red[16 + row]), fmaxf(red[32 + row], red[48 + row]));
    }

    // rare-path detector: visible max <= -5000 <=> whole visible span is
    // padding-masked, so causal-masked (~-1e4) scores participate in softmax.
    float mn = fminf(fminf(rmax[0], rmax[1]), fminf(rmax[2], rmax[3]));
    mn = fminf(mn, __shfl_xor(mn, 16, 64));
    mn = fminf(mn, __shfl_xor(mn, 32, 64));
    const bool needfull = (mn <= -5000.0f);        // block-uniform
    int Jmax = qtr;

    if (needfull) {
        __syncthreads();                            // red[0..63] readers done
#pragma unroll
        for (int g = 0; g < 8; g++) {
            if (g > gq) {
#pragma unroll
                for (int tp = 0; tp < 4; tp++) {
                    const int t = g * 4 + tp;
                    const int n0 = (t * 4 + wave) * 16;
                    const bf16* kb = &krow[(size_t)(n0 + m16) * DKc + quad * 8];
                    bf16x8 b0 = *(const bf16x8*)kb;
                    bf16x8 b1 = *(const bf16x8*)(kb + 32);
                    acc[t] = __builtin_amdgcn_mfma_f32_16x16x32_bf16(aq0, b0, acc[t], 0, 0, 0);
                    acc[t] = __builtin_amdgcn_mfma_f32_16x16x32_bf16(aq1, b1, acc[t], 0, 0, 0);
                }
            }
        }
#pragma unroll
        for (int t = 0; t < 32; t++) {
            const int j = t * 4 + wave;
            if (j > qtr) {
                const int kcol = j * 16 + m16;
#pragma unroll
                for (int r = 0; r < 4; r++) {
                    const int grow = q0 + quad * 4 + r;
                    const int mv = mrow[(size_t)grow * Sc + kcol];
                    float s = acc[t][r] * 0.125f;
                    s += (mv == 0) ? NEGc : 0.f;
                    s += (kcol > grow) ? NEGc : 0.f;
                    acc[t][r] = s;
                    rmax[r] = fmaxf(rmax[r], s);
                }
            }
        }
#pragma unroll
        for (int off = 1; off < 16; off <<= 1)
#pragma unroll
            for (int r = 0; r < 4; r++) rmax[r] = fmaxf(rmax[r], __shfl_xor(rmax[r], off, 64));
        if (m16 == 0) {
#pragma unroll
            for (int r = 0; r < 4; r++) red[wave * 16 + quad * 4 + r] = rmax[r];
        }
        __syncthreads();
#pragma unroll
        for (int r = 0; r < 4; r++) {
            const int row = quad * 4 + r;
            rmax[r] = fmaxf(fmaxf(red[row], red[16 + row]), fmaxf(red[32 + row], red[48 + row]));
        }
        Jmax = 127;
    }

    // ---- exp + sum over live tiles ----
    float rsum[4] = {0.f, 0.f, 0.f, 0.f};
#pragma unroll
    for (int t = 0; t < 32; t++) {
        const int j = t * 4 + wave;
        if (j <= Jmax) {
#pragma unroll
            for (int r = 0; r < 4; r++) {
                float e = __expf(acc[t][r] - rmax[r]);
                acc[t][r] = e;
                rsum[r] += e;
            }
        }
    }
#pragma unroll
    for (int off = 1; off < 16; off <<= 1)
#pragma unroll
        for (int r = 0; r < 4; r++) rsum[r] += __shfl_xor(rsum[r], off, 64);
    if (m16 == 0) {
#pragma unroll
        for (int r = 0; r < 4; r++) red[64 + wave * 16 + quad * 4 + r] = rsum[r];
    }
    __syncthreads();
    float inv[4];
#pragma unroll
    for (int r = 0; r < 4; r++) {
        const int row = quad * 4 + r;
        inv[r] = 1.0f / (red[64 + row] + red[80 + row] + red[96 + row] + red[112 + row]);
    }

    // ---- normalized probs: NT fp32 to global; acc overwritten with p ----
    float* arow_base = attn_out + ((size_t)bh * Sc + q0) * Sc;
#pragma unroll
    for (int t = 0; t < 32; t++) {
        const int j = t * 4 + wave;
        if (j <= Jmax) {
            const int kcol = j * 16 + m16;
#pragma unroll
            for (int r = 0; r < 4; r++) {
                const int row = quad * 4 + r;
                const float p = acc[t][r] * inv[r];
                acc[t][r] = p;
                __builtin_nontemporal_store(p, &arow_base[(size_t)row * Sc + kcol]);
            }
        }
    }
    // zero-fill the causal-dead region (exact in fp32), vectorized NT f32x4
    if (!needfull) {
        const int z0 = (qtr + 1) * 16;
        const int c4n = (Sc - z0) >> 2;
#pragma unroll
        for (int r = 0; r < 16; r++) {
            float* rp = arow_base + (size_t)r * Sc + z0;
            for (int c = tid; c < c4n; c += 256)
                __builtin_nontemporal_store(zero4, (f32x4*)(rp + 4 * c));
        }
    }

    // ---- PV over live 256-key chunks: LDS-stage bf16 probs, MFMA vs V^T ----
    const int dcol = wave * 16 + m16;
    const bf16* vbase = &vrow[(size_t)dcol * Sc];
    const int swz = (m16 & 7) << 3;
    f32x4 oacc = zero4;
#pragma unroll
    for (int c = 0; c < 8; c++) {
        if (c * 16 <= Jmax) {
            __syncthreads();                    // prev chunk's reads done
#pragma unroll
            for (int tp = 0; tp < 4; tp++) {
                const int t = c * 4 + tp;
                const int j = t * 4 + wave;
                const int lc = (tp * 4 + wave) * 16 + m16;   // chunk-local col
                if (j <= Jmax) {
#pragma unroll
                    for (int r = 0; r < 4; r++) {
                        const int row = quad * 4 + r;
                        sc[row][lc ^ ((row & 7) << 3)] = (bf16)acc[t][r];
                    }
                } else if (j <= (Jmax | 1)) {   // odd partner of a live 32-key group
#pragma unroll
                    for (int r = 0; r < 4; r++) {
                        const int row = quad * 4 + r;
                        sc[row][lc ^ ((row & 7) << 3)] = (bf16)0.f;
                    }
                }
            }
            __syncthreads();
#pragma unroll
            for (int lks = 0; lks < 8; lks++) {
                if (c * 16 + 2 * lks <= Jmax) {
                    const int k0 = lks * 32 + quad * 8;
                    bf16x8 a  = *(const bf16x8*)&sc[m16][k0 ^ swz];
                    bf16x8 b8 = *(const bf16x8*)&vbase[c * 256 + k0];
                    oacc = __builtin_amdgcn_mfma_f32_16x16x32_bf16(a, b8, oacc, 0, 0, 0);
                }
            }
        }
    }
    float* obase = out + ((size_t)(b * Sc + q0)) * Dc + h * DKc;
#pragma unroll
    for (int r = 0; r < 4; r++) {
        const int row = quad * 4 + r;
        obase[(size_t)row * Dc + dcol] = oacc[r];
    }
}

// ---------------------------------------------------------------------------
// Kernel 4: residual add + LayerNorm, in place on d_out's `out` region.
// ---------------------------------------------------------------------------
__global__ __launch_bounds__(256) void ln_kernel(float* __restrict__ out,
                                                 const float* __restrict__ resid,
                                                 const float* __restrict__ gw,
                                                 const float* __restrict__ bw)
{
    const int row = blockIdx.x, tid = threadIdx.x;
    float* orow = out + (size_t)row * Dc;
    const float* rrow = resid + (size_t)row * Dc;
    float4 x = *(const float4*)&orow[tid * 4];
    float4 rr = *(const float4*)&rrow[tid * 4];
    x.x += rr.x; x.y += rr.y; x.z += rr.z; x.w += rr.w;
    float s1 = x.x + x.y + x.z + x.w;
    float s2 = x.x * x.x + x.y * x.y + x.z * x.z + x.w * x.w;
#pragma unroll
    for (int off = 1; off < 64; off <<= 1) {
        s1 += __shfl_xor(s1, off, 64);
        s2 += __shfl_xor(s2, off, 64);
    }
    __shared__ float red[8];
    const int wave = tid >> 6, lane = tid & 63;
    if (lane == 0) { red[wave] = s1; red[4 + wave] = s2; }
    __syncthreads();
    s1 = red[0] + red[1] + red[2] + red[3];
    s2 = red[4] + red[5] + red[6] + red[7];
    const float mu = s1 * (1.f / Dc);
    const float var = s2 * (1.f / Dc) - mu * mu;
    const float rstd = rsqrtf(var + 1e-5f);
    float4 g4 = *(const float4*)&gw[tid * 4];
    float4 b4 = *(const float4*)&bw[tid * 4];
    float4 y;
    y.x = (x.x - mu) * rstd * g4.x + b4.x;
    y.y = (x.y - mu) * rstd * g4.y + b4.y;
    y.z = (x.z - mu) * rstd * g4.z + b4.z;
    y.w = (x.w - mu) * rstd * g4.w + b4.w;
    *(float4*)&orow[tid * 4] = y;
}

// ---------------------------------------------------------------------------
extern "C" void kernel_launch(void* const* d_in, const int* in_sizes, int n_in,
                              void* d_out, int out_size, void* d_ws, size_t ws_size,
                              hipStream_t stream)
{
    (void)in_sizes; (void)n_in; (void)out_size; (void)ws_size;
    const float* q    = (const float*)d_in[0];
    const float* k    = (const float*)d_in[1];
    const float* v    = (const float*)d_in[2];
    const int*   mask = (const int*)d_in[3];
    const float* Wq   = (const float*)d_in[4];
    const float* bq   = (const float*)d_in[5];
    const float* Wk   = (const float*)d_in[6];
    const float* bk   = (const float*)d_in[7];
    const float* Wv   = (const float*)d_in[8];
    const float* bv   = (const float*)d_in[9];
    const float* g    = (const float*)d_in[10];
    const float* bet  = (const float*)d_in[11];

    float* out  = (float*)d_out;                     // [B,S,D]
    float* attn = out + (size_t)Bc * Sc * Dc;        // [B,H,S,S]

    const size_t headN = (size_t)Bc * Hc * Sc * DKc; // 8.39M bf16 = 16 MB
    bf16* qh = (bf16*)d_ws;
    bf16* kh = qh + headN;
    bf16* vh = kh + headN;
    bf16* vt = vh + headN;

    proj_kernel<<<dim3(8, 64, 3), 256, 0, stream>>>(q, k, v, Wq, bq, Wk, bk, Wv, bv, qh, kh, vh);
    vtrans_kernel<<<dim3(Sc / 64, Bc * Hc), 256, 0, stream>>>(vh, vt);
    attn_kernel<<<dim3(Sc / 16, Hc, Bc), 256, 0, stream>>>(qh, kh, vt, mask, attn, out);
    ln_kernel<<<dim3(Bc * Sc), 256, 0, stream>>>(out, q, g, bet);
}

// Round 4
// 1583.019 us; speedup vs baseline: 1.1484x; 1.0531x over previous
//
#include <hip/hip_runtime.h>

typedef __bf16 bf16;
typedef float f32x4 __attribute__((ext_vector_type(4)));
typedef bf16 bf16x8 __attribute__((ext_vector_type(8)));
typedef bf16 bf16x4 __attribute__((ext_vector_type(4)));
typedef unsigned int u32;
typedef unsigned char u8;

constexpr int Bc = 4, Sc = 2048, Dc = 1024, Hc = 16, DKc = 64;
constexpr float NEGc = -10000.0f;

// ---------------------------------------------------------------------------
// Kernel 0: f32 -> bf16 convert for q/k/v (z=0..2) and Wq/Wk/Wv (z=3..5).
// Outputs live in the (not-yet-written) attn region of d_out — dead space
// until attn_kernel overwrites it, stream-ordered.
// ---------------------------------------------------------------------------
__global__ __launch_bounds__(256) void cvt_kernel(
    const float* __restrict__ xq, const float* __restrict__ xk, const float* __restrict__ xv,
    const float* __restrict__ Wq, const float* __restrict__ Wk, const float* __restrict__ Wv,
    bf16* __restrict__ xbq, bf16* __restrict__ xbk, bf16* __restrict__ xbv,
    bf16* __restrict__ wbq, bf16* __restrict__ wbk, bf16* __restrict__ wbv)
{
    const int z = blockIdx.y;
    const float* src = (z == 0) ? xq : (z == 1) ? xk : (z == 2) ? xv
                      : (z == 3) ? Wq : (z == 4) ? Wk : Wv;
    bf16* dst = (z == 0) ? xbq : (z == 1) ? xbk : (z == 2) ? xbv
               : (z == 3) ? wbq : (z == 4) ? wbk : wbv;
    const int n4 = ((z < 3) ? (Bc * Sc * Dc) : (Dc * Dc)) >> 2;
    const int stride = gridDim.x * 256;
    for (int i = blockIdx.x * 256 + threadIdx.x; i < n4; i += stride) {
        float4 v = ((const float4*)src)[i];
        bf16x4 o; o.x = (bf16)v.x; o.y = (bf16)v.y; o.z = (bf16)v.z; o.w = (bf16)v.w;
        ((bf16x4*)dst)[i] = o;
    }
}

// ---------------------------------------------------------------------------
// Kernel 0b: pack mask [B,S,S] i32 -> u8 [B,S, m16(16), wave(4), t(32)] so the
// attn consumer (lane m16, wave, tiles t) reads 32 consecutive bytes per row.
// byte((b,row), m16, wv, t) = mask[b,row,(t*4+wv)*16+m16] != 0
// ---------------------------------------------------------------------------
__global__ __launch_bounds__(256) void pack_kernel(const int* __restrict__ mask,
                                                   u8* __restrict__ mp)
{
    const int row = blockIdx.x;                 // b*Sc + s
    const int tid = threadIdx.x;
    __shared__ u8 lm[2048];
    const int4* src = (const int4*)(mask + (size_t)row * Sc);
#pragma unroll
    for (int i = 0; i < 2; i++) {
        int4 v = src[tid * 2 + i];
        const int o = tid * 8 + i * 4;
        lm[o + 0] = (u8)(v.x != 0); lm[o + 1] = (u8)(v.y != 0);
        lm[o + 2] = (u8)(v.z != 0); lm[o + 3] = (u8)(v.w != 0);
    }
    __syncthreads();
    u32 w0 = 0, w1 = 0;
#pragma unroll
    for (int i = 0; i < 8; i++) {
        const int o = tid * 8 + i;
        const int m16 = o >> 7, wv = (o >> 5) & 3, t = o & 31;
        const u32 bv = lm[(t * 4 + wv) * 16 + m16];
        if (i < 4) w0 |= bv << (8 * i); else w1 |= bv << (8 * (i - 4));
    }
    ((uint2*)(mp + (size_t)row * 2048))[tid] = make_uint2(w0, w1);
}

// ---------------------------------------------------------------------------
// Kernel 1: QKV projection GEMM, bf16 inputs (pre-converted).  y = x@W^T + b.
// 128x128 tile, BK=32, 4 waves 2x2; staging is pure bf16x8 copies (no cvt in
// the K-loop — R3's fp32 staging was VALU-bound at ~172 TF).
// ---------------------------------------------------------------------------
__global__ __launch_bounds__(256, 2) void projb_kernel(
    const bf16* __restrict__ xq, const bf16* __restrict__ xk, const bf16* __restrict__ xv,
    const bf16* __restrict__ Wq, const float* __restrict__ bq,
    const bf16* __restrict__ Wk, const float* __restrict__ bk,
    const bf16* __restrict__ Wv, const float* __restrict__ bv,
    bf16* __restrict__ qh, bf16* __restrict__ kh, bf16* __restrict__ vh)
{
    const int z = blockIdx.z;
    const bf16* x     = (z == 0) ? xq : (z == 1) ? xk : xv;
    const bf16* W     = (z == 0) ? Wq : (z == 1) ? Wk : Wv;
    const float* bias = (z == 0) ? bq : (z == 1) ? bk : bv;
    bf16* dst         = (z == 0) ? qh : (z == 1) ? kh : vh;

    const int tid = threadIdx.x;
    const int wave = tid >> 6, lane = tid & 63, quad = lane >> 4, m16 = lane & 15;
    const int wm = (wave >> 1) * 64, wn = (wave & 1) * 64;
    const int m0 = blockIdx.y * 128, n0 = blockIdx.x * 128;

    __shared__ bf16 As[128][40];
    __shared__ bf16 Bs[128][40];

    const f32x4 zero4 = {0.f, 0.f, 0.f, 0.f};
    f32x4 acc[4][4];
#pragma unroll
    for (int i = 0; i < 4; i++)
#pragma unroll
        for (int j = 0; j < 4; j++) acc[i][j] = zero4;

    for (int kk = 0; kk < 32; ++kk) {
        const int k0 = kk * 32;
#pragma unroll
        for (int i = 0; i < 2; i++) {
            int v8 = tid + i * 256;            // 0..511 vec8 slots (128 rows x 4)
            int r = v8 >> 2, c8 = (v8 & 3) * 8;
            *(bf16x8*)&As[r][c8] = *(const bf16x8*)&x[(size_t)(m0 + r) * Dc + k0 + c8];
            *(bf16x8*)&Bs[r][c8] = *(const bf16x8*)&W[(size_t)(n0 + r) * Dc + k0 + c8];
        }
        __syncthreads();
        bf16x8 af[4], bfr[4];
#pragma unroll
        for (int t = 0; t < 4; t++) {
            af[t]  = *(const bf16x8*)&As[wm + t * 16 + m16][quad * 8];
            bfr[t] = *(const bf16x8*)&Bs[wn + t * 16 + m16][quad * 8];
        }
#pragma unroll
        for (int mt = 0; mt < 4; mt++)
#pragma unroll
            for (int nt = 0; nt < 4; nt++)
                acc[mt][nt] = __builtin_amdgcn_mfma_f32_16x16x32_bf16(af[mt], bfr[nt], acc[mt][nt], 0, 0, 0);
        __syncthreads();
    }

#pragma unroll
    for (int nt = 0; nt < 4; nt++) {
        int n = n0 + wn + nt * 16 + m16;
        float bval = bias[n];
        int h = n >> 6, d = n & 63;
#pragma unroll
        for (int mt = 0; mt < 4; mt++) {
#pragma unroll
            for (int r = 0; r < 4; r++) {
                int m = m0 + wm + mt * 16 + quad * 4 + r;
                int bb = m >> 11, s = m & 2047;
                float val = acc[mt][nt][r] + bval;
                dst[(((size_t)(bb * Hc + h)) * Sc + s) * DKc + d] = (bf16)val;
            }
        }
    }
}

// ---------------------------------------------------------------------------
// Kernel 2: transpose V  [B,H,S,64] -> [B,H,64,S]
// ---------------------------------------------------------------------------
__global__ __launch_bounds__(256) void vtrans_kernel(const bf16* __restrict__ vh,
                                                     bf16* __restrict__ vt)
{
    const int tid = threadIdx.x;
    const int bh = blockIdx.y, s0 = blockIdx.x * 64;
    __shared__ bf16 tile[64][72];
    const bf16* src = vh + ((size_t)bh * Sc + s0) * DKc;
#pragma unroll
    for (int i = 0; i < 2; i++) {
        int v = tid + i * 256;
        int sl = v >> 3, d8 = (v & 7) * 8;
        *(bf16x8*)&tile[sl][d8] = *(const bf16x8*)&src[sl * DKc + d8];
    }
    __syncthreads();
#pragma unroll
    for (int i = 0; i < 2; i++) {
        int v = tid + i * 256;
        int d = v >> 3, s8 = (v & 7) * 8;
        bf16x8 o;
#pragma unroll
        for (int j = 0; j < 8; j++) o[j] = tile[s8 + j][d];
        *(bf16x8*)&vt[((size_t)bh * DKc + d) * Sc + s0 + s8] = o;
    }
}

// ---------------------------------------------------------------------------
// Kernel 3: attention.  Causal-dead upper region skipped exactly (needfull
// fallback).  PACKED: mask bytes pre-packed, 8 vec16 loads/lane issued before
// QK^T.  PV: double-buffered 2x8KB prob chunks (1 barrier/chunk) with prob
// global-stores fused into staging so the 1.07 GB NT stream overlaps MFMA.
// __launch_bounds__(256,2): acc[32] f32x4 = 128 VGPR must not spill.
// ---------------------------------------------------------------------------
template<bool PACKED>
__global__ __launch_bounds__(256, 2) void attn_kernel(
    const bf16* __restrict__ qh, const bf16* __restrict__ kh, const bf16* __restrict__ vt,
    const int* __restrict__ mask, const u8* __restrict__ mp,
    float* __restrict__ attn_out, float* __restrict__ out)
{
    const int qtr = (int)gridDim.x - 1 - (int)blockIdx.x;   // heavy blocks first
    const int h = blockIdx.y, b = blockIdx.z;
    const int bh = b * Hc + h, q0 = qtr * 16;
    const int tid = threadIdx.x;
    const int wave = tid >> 6, lane = tid & 63, quad = lane >> 4, m16 = lane & 15;

    __shared__ bf16 sc[2][16][256];     // double-buffered prob chunk, 16 KB
    __shared__ float red[128];

    const bf16* qrow = qh + ((size_t)bh * Sc + q0) * DKc;
    const bf16* krow = kh + (size_t)bh * Sc * DKc;
    const bf16* vrow = vt + (size_t)bh * DKc * Sc;

    const bf16x8 aq0 = *(const bf16x8*)&qrow[m16 * DKc + quad * 8];
    const bf16x8 aq1 = *(const bf16x8*)&qrow[m16 * DKc + 32 + quad * 8];

    // packed mask bytes: 4 rows x 32 B, covers all 128 tiles; issued early so
    // they complete under the QK^T MFMAs.
    u32 mw[4][8];
    if constexpr (PACKED) {
#pragma unroll
        for (int r = 0; r < 4; r++) {
            const int grow = q0 + quad * 4 + r;
            const u8* p = mp + ((size_t)b * Sc + grow) * 2048 + m16 * 128 + wave * 32;
            uint4 a = *(const uint4*)p, c = *(const uint4*)(p + 16);
            mw[r][0] = a.x; mw[r][1] = a.y; mw[r][2] = a.z; mw[r][3] = a.w;
            mw[r][4] = c.x; mw[r][5] = c.y; mw[r][6] = c.z; mw[r][7] = c.w;
        }
    }

    const f32x4 zero4 = {0.f, 0.f, 0.f, 0.f};
    f32x4 acc[32];
#pragma unroll
    for (int t = 0; t < 32; t++) acc[t] = zero4;

    const int gq = qtr >> 4;

    // ---- QK^T over live 256-key chunks ----
#pragma unroll
    for (int g = 0; g < 8; g++) {
        if (g <= gq) {
#pragma unroll
            for (int tp = 0; tp < 4; tp++) {
                const int t = g * 4 + tp;
                const int n0 = (t * 4 + wave) * 16;
                const bf16* kb = &krow[(size_t)(n0 + m16) * DKc + quad * 8];
                bf16x8 b0 = *(const bf16x8*)kb;
                bf16x8 b1 = *(const bf16x8*)(kb + 32);
                acc[t] = __builtin_amdgcn_mfma_f32_16x16x32_bf16(aq0, b0, acc[t], 0, 0, 0);
                acc[t] = __builtin_amdgcn_mfma_f32_16x16x32_bf16(aq1, b1, acc[t], 0, 0, 0);
            }
        }
    }

    // ---- scale + mask adders + running max over j <= qtr ----
    float rmax[4] = {-3e38f, -3e38f, -3e38f, -3e38f};
#pragma unroll
    for (int t = 0; t < 32; t++) {
        const int j = t * 4 + wave;
        if (j <= qtr) {
            const int kcol = j * 16 + m16;
#pragma unroll
            for (int r = 0; r < 4; r++) {
                const int grow = q0 + quad * 4 + r;
                float s;
                if constexpr (PACKED) {
                    const float bf = (float)((mw[r][t >> 2] >> ((t & 3) * 8)) & 0xffu);
                    s = fmaf(bf, 10000.0f, NEGc) + acc[t][r] * 0.125f;   // 0 or -1e4, exact
                } else {
                    const int mv = mask[((size_t)b * Sc + grow) * Sc + kcol];
                    s = acc[t][r] * 0.125f + ((mv == 0) ? NEGc : 0.f);
                }
                s += (kcol > grow) ? NEGc : 0.f;
                acc[t][r] = s;
                rmax[r] = fmaxf(rmax[r], s);
            }
        }
    }
#pragma unroll
    for (int off = 1; off < 16; off <<= 1)
#pragma unroll
        for (int r = 0; r < 4; r++) rmax[r] = fmaxf(rmax[r], __shfl_xor(rmax[r], off, 64));
    if (m16 == 0) {
#pragma unroll
        for (int r = 0; r < 4; r++) red[wave * 16 + quad * 4 + r] = rmax[r];
    }
    __syncthreads();
#pragma unroll
    for (int r = 0; r < 4; r++) {
        const int row = quad * 4 + r;
        rmax[r] = fmaxf(fmaxf(red[row], red[16 + row]), fmaxf(red[32 + row], red[48 + row]));
    }

    // rare-path detector (visible span fully padding-masked)
    float mn = fminf(fminf(rmax[0], rmax[1]), fminf(rmax[2], rmax[3]));
    mn = fminf(mn, __shfl_xor(mn, 16, 64));
    mn = fminf(mn, __shfl_xor(mn, 32, 64));
    const bool needfull = (mn <= -5000.0f);        // block-uniform
    int Jmax = qtr;

    if (needfull) {
        __syncthreads();
#pragma unroll
        for (int g = 0; g < 8; g++) {
            if (g > gq) {
#pragma unroll
                for (int tp = 0; tp < 4; tp++) {
                    const int t = g * 4 + tp;
                    const int n0 = (t * 4 + wave) * 16;
                    const bf16* kb = &krow[(size_t)(n0 + m16) * DKc + quad * 8];
                    bf16x8 b0 = *(const bf16x8*)kb;
                    bf16x8 b1 = *(const bf16x8*)(kb + 32);
                    acc[t] = __builtin_amdgcn_mfma_f32_16x16x32_bf16(aq0, b0, acc[t], 0, 0, 0);
                    acc[t] = __builtin_amdgcn_mfma_f32_16x16x32_bf16(aq1, b1, acc[t], 0, 0, 0);
                }
            }
        }
#pragma unroll
        for (int t = 0; t < 32; t++) {
            const int j = t * 4 + wave;
            if (j > qtr) {
                const int kcol = j * 16 + m16;
#pragma unroll
                for (int r = 0; r < 4; r++) {
                    const int grow = q0 + quad * 4 + r;
                    float s;
                    if constexpr (PACKED) {
                        const float bf = (float)((mw[r][t >> 2] >> ((t & 3) * 8)) & 0xffu);
                        s = fmaf(bf, 10000.0f, NEGc) + acc[t][r] * 0.125f;
                    } else {
                        const int mv = mask[((size_t)b * Sc + grow) * Sc + kcol];
                        s = acc[t][r] * 0.125f + ((mv == 0) ? NEGc : 0.f);
                    }
                    s += (kcol > grow) ? NEGc : 0.f;
                    acc[t][r] = s;
                    rmax[r] = fmaxf(rmax[r], s);
                }
            }
        }
#pragma unroll
        for (int off = 1; off < 16; off <<= 1)
#pragma unroll
            for (int r = 0; r < 4; r++) rmax[r] = fmaxf(rmax[r], __shfl_xor(rmax[r], off, 64));
        if (m16 == 0) {
#pragma unroll
            for (int r = 0; r < 4; r++) red[wave * 16 + quad * 4 + r] = rmax[r];
        }
        __syncthreads();
#pragma unroll
        for (int r = 0; r < 4; r++) {
            const int row = quad * 4 + r;
            rmax[r] = fmaxf(fmaxf(red[row], red[16 + row]), fmaxf(red[32 + row], red[48 + row]));
        }
        Jmax = 127;
    }

    // ---- exp + sum over live tiles ----
    float rsum[4] = {0.f, 0.f, 0.f, 0.f};
#pragma unroll
    for (int t = 0; t < 32; t++) {
        const int j = t * 4 + wave;
        if (j <= Jmax) {
#pragma unroll
            for (int r = 0; r < 4; r++) {
                float e = __expf(acc[t][r] - rmax[r]);
                acc[t][r] = e;
                rsum[r] += e;
            }
        }
    }
#pragma unroll
    for (int off = 1; off < 16; off <<= 1)
#pragma unroll
        for (int r = 0; r < 4; r++) rsum[r] += __shfl_xor(rsum[r], off, 64);
    if (m16 == 0) {
#pragma unroll
        for (int r = 0; r < 4; r++) red[64 + wave * 16 + quad * 4 + r] = rsum[r];
    }
    __syncthreads();
    float inv[4];
#pragma unroll
    for (int r = 0; r < 4; r++) {
        const int row = quad * 4 + r;
        inv[r] = 1.0f / (red[64 + row] + red[80 + row] + red[96 + row] + red[112 + row]);
    }

    // ---- PV over live chunks, double-buffered; prob NT stores fused in ----
    const int dcol = wave * 16 + m16;
    const bf16* vbase = &vrow[(size_t)dcol * Sc];
    const int swz = (m16 & 7) << 3;
    float* arow_base = attn_out + ((size_t)bh * Sc + q0) * Sc;
    f32x4 oacc = zero4;
#pragma unroll
    for (int c = 0; c < 8; c++) {
        if (c * 16 <= Jmax) {
            const int cb = c & 1;
#pragma unroll
            for (int tp = 0; tp < 4; tp++) {
                const int t = c * 4 + tp;
                const int j = t * 4 + wave;
                const int lc = (tp * 4 + wave) * 16 + m16;
                if (j <= Jmax) {
                    const int kcol = j * 16 + m16;
#pragma unroll
                    for (int r = 0; r < 4; r++) {
                        const int row = quad * 4 + r;
                        const float p = acc[t][r] * inv[r];
                        __builtin_nontemporal_store(p, &arow_base[(size_t)row * Sc + kcol]);
                        sc[cb][row][lc ^ ((row & 7) << 3)] = (bf16)p;
                    }
                } else if (j <= (Jmax | 1)) {    // odd partner of a live pair
#pragma unroll
                    for (int r = 0; r < 4; r++) {
                        const int row = quad * 4 + r;
                        sc[cb][row][lc ^ ((row & 7) << 3)] = (bf16)0.f;
                    }
                }
            }
            __syncthreads();                     // one barrier per chunk (dbuf)
#pragma unroll
            for (int lks = 0; lks < 8; lks++) {
                if (c * 16 + 2 * lks <= Jmax) {
                    const int k0 = lks * 32 + quad * 8;
                    bf16x8 a  = *(const bf16x8*)&sc[cb][m16][k0 ^ swz];
                    bf16x8 b8 = *(const bf16x8*)&vbase[c * 256 + k0];
                    oacc = __builtin_amdgcn_mfma_f32_16x16x32_bf16(a, b8, oacc, 0, 0, 0);
                }
            }
        }
    }
    float* obase = out + ((size_t)(b * Sc + q0)) * Dc + h * DKc;
#pragma unroll
    for (int r = 0; r < 4; r++) {
        const int row = quad * 4 + r;
        obase[(size_t)row * Dc + dcol] = oacc[r];
    }

    // ---- zero-fill the causal-dead region (exact), after the critical path ----
    if (!needfull) {
        const int z0 = (qtr + 1) * 16;
        const int c4n = (Sc - z0) >> 2;
#pragma unroll
        for (int r = 0; r < 16; r++) {
            float* rp = arow_base + (size_t)r * Sc + z0;
            for (int c = tid; c < c4n; c += 256)
                __builtin_nontemporal_store(zero4, (f32x4*)(rp + 4 * c));
        }
    }
}

// ---------------------------------------------------------------------------
// Kernel 4: residual add + LayerNorm
// ---------------------------------------------------------------------------
__global__ __launch_bounds__(256) void ln_kernel(float* __restrict__ out,
                                                 const float* __restrict__ resid,
                                                 const float* __restrict__ gw,
                                                 const float* __restrict__ bw)
{
    const int row = blockIdx.x, tid = threadIdx.x;
    float* orow = out + (size_t)row * Dc;
    const float* rrow = resid + (size_t)row * Dc;
    float4 x = *(const float4*)&orow[tid * 4];
    float4 rr = *(const float4*)&rrow[tid * 4];
    x.x += rr.x; x.y += rr.y; x.z += rr.z; x.w += rr.w;
    float s1 = x.x + x.y + x.z + x.w;
    float s2 = x.x * x.x + x.y * x.y + x.z * x.z + x.w * x.w;
#pragma unroll
    for (int off = 1; off < 64; off <<= 1) {
        s1 += __shfl_xor(s1, off, 64);
        s2 += __shfl_xor(s2, off, 64);
    }
    __shared__ float red[8];
    const int wave = tid >> 6, lane = tid & 63;
    if (lane == 0) { red[wave] = s1; red[4 + wave] = s2; }
    __syncthreads();
    s1 = red[0] + red[1] + red[2] + red[3];
    s2 = red[4] + red[5] + red[6] + red[7];
    const float mu = s1 * (1.f / Dc);
    const float var = s2 * (1.f / Dc) - mu * mu;
    const float rstd = rsqrtf(var + 1e-5f);
    float4 g4 = *(const float4*)&gw[tid * 4];
    float4 b4 = *(const float4*)&bw[tid * 4];
    float4 y;
    y.x = (x.x - mu) * rstd * g4.x + b4.x;
    y.y = (x.y - mu) * rstd * g4.y + b4.y;
    y.z = (x.z - mu) * rstd * g4.z + b4.z;
    y.w = (x.w - mu) * rstd * g4.w + b4.w;
    *(float4*)&orow[tid * 4] = y;
}

// ---------------------------------------------------------------------------
extern "C" void kernel_launch(void* const* d_in, const int* in_sizes, int n_in,
                              void* d_out, int out_size, void* d_ws, size_t ws_size,
                              hipStream_t stream)
{
    (void)in_sizes; (void)n_in; (void)out_size;
    const float* q    = (const float*)d_in[0];
    const float* k    = (const float*)d_in[1];
    const float* v    = (const float*)d_in[2];
    const int*   mask = (const int*)d_in[3];
    const float* Wq   = (const float*)d_in[4];
    const float* bq   = (const float*)d_in[5];
    const float* Wk   = (const float*)d_in[6];
    const float* bk   = (const float*)d_in[7];
    const float* Wv   = (const float*)d_in[8];
    const float* bv   = (const float*)d_in[9];
    const float* g    = (const float*)d_in[10];
    const float* bet  = (const float*)d_in[11];

    float* out  = (float*)d_out;                     // [B,S,D]
    float* attn = out + (size_t)Bc * Sc * Dc;        // [B,H,S,S]

    const size_t headN = (size_t)Bc * Hc * Sc * DKc; // 8.39M elems, 16 MB bf16
    bf16* qh = (bf16*)d_ws;
    bf16* kh = qh + headN;
    bf16* vh = kh + headN;
    bf16* vt = vh + headN;
    u8*   mp = (u8*)(vt + headN);                    // +16.8 MB if ws allows
    const bool packed = ws_size >= 4 * headN * sizeof(bf16) + (size_t)Bc * Sc * Sc;

    // bf16 scratch lives in the attn region of d_out (dead until attn_kernel,
    // stream-ordered): 3x16.8 MB (x) + 3x2.1 MB (W) << 1.07 GB.
    const size_t XN = (size_t)Bc * Sc * Dc;
    bf16* xbq = (bf16*)attn;
    bf16* xbk = xbq + XN;
    bf16* xbv = xbk + XN;
    bf16* wbq = xbv + XN;
    bf16* wbk = wbq + (size_t)Dc * Dc;
    bf16* wbv = wbk + (size_t)Dc * Dc;

    cvt_kernel<<<dim3(1024, 6), 256, 0, stream>>>(q, k, v, Wq, Wk, Wv,
                                                  xbq, xbk, xbv, wbq, wbk, wbv);
    if (packed) pack_kernel<<<dim3(Bc * Sc), 256, 0, stream>>>(mask, mp);
    projb_kernel<<<dim3(8, 64, 3), 256, 0, stream>>>(xbq, xbk, xbv, wbq, bq, wbk, bk, wbv, bv,
                                                     qh, kh, vh);
    vtrans_kernel<<<dim3(Sc / 64, Bc * Hc), 256, 0, stream>>>(vh, vt);
    if (packed)
        attn_kernel<true><<<dim3(Sc / 16, Hc, Bc), 256, 0, stream>>>(qh, kh, vt, mask, mp, attn, out);
    else
        attn_kernel<false><<<dim3(Sc / 16, Hc, Bc), 256, 0, stream>>>(qh, kh, vt, mask, mp, attn, out);
    ln_kernel<<<dim3(Bc * Sc), 256, 0, stream>>>(out, q, g, bet);
}